// Round 8
// baseline (27952.982 us; speedup 1.0000x reference)
//
#include <hip/hip_runtime.h>
#include <stdint.h>

// R8: R7 (tagged-h ring, fence-free bypassing atomics, distributed epilogue)
//     + R4's AGPR weight residency (v_accvgpr_write once, volatile
//     v_accvgpr_read in the dot loop). R4 counters prove AGPRs stay resident
//     (AGPR class has no competing users); this removes the 256 KB/CU/step
//     scratch/L2 weight restream that dominated R5-R7's 3 us cadence.

#define S_LEN 8192
#define HID   1024
#define DIN0  256
#define NL    4
#define NCU_L 64
#define NTHR  512
#define NWAVE 8
#define SP    128          // weight dwords per lane per wave
#define RING  1024
#define RMASK (RING - 1)

typedef _Float16 half2v __attribute__((ext_vector_type(2)));
typedef uint32_t v4u   __attribute__((ext_vector_type(4)));

#if defined(__has_builtin)
#if __has_builtin(__builtin_amdgcn_fdot2)
#define HAVE_FDOT2 1
#endif
#endif

__device__ __forceinline__ float dot2acc(uint32_t w, uint32_t x, float acc) {
#ifdef HAVE_FDOT2
    return __builtin_amdgcn_fdot2(__builtin_bit_cast(half2v, w),
                                  __builtin_bit_cast(half2v, x), acc, false);
#else
    half2v hw = __builtin_bit_cast(half2v, w);
    half2v hx = __builtin_bit_cast(half2v, x);
    return acc + (float)hw.x * (float)hx.x + (float)hw.y * (float)hx.y;
#endif
}

#define ALOAD(p)      __hip_atomic_load((p), __ATOMIC_RELAXED, __HIP_MEMORY_SCOPE_AGENT)
#define ASTORE(p, v)  __hip_atomic_store((p), (v), __ATOMIC_RELAXED, __HIP_MEMORY_SCOPE_AGENT)

// ---- workspace layout ----
constexpr size_t X0_DW   = (size_t)S_LEN * (DIN0 / 2);            // 4 MB
constexpr size_t X0B     = X0_DW * 4;
constexpr size_t RING_DW = (size_t)NL * RING * HID;               // tagged dwords, 16 MB
constexpr size_t RINGB   = RING_DW * 4;
constexpr size_t WK_DW   = (size_t)NWAVE * SP * 64;               // 65536 dw per block
constexpr size_t WL_DW   = (size_t)NCU_L * WK_DW;
constexpr size_t WB      = (size_t)NL * WL_DW * 4;                // ~67 MB
constexpr size_t FLAG_N  = (size_t)NL * NCU_L + 1;                // prog[4][64] + abort
constexpr size_t TOTAL_WS = X0B + RINGB + WB + FLAG_N * 4;

// ---------------- pre-kernels ----------------

__global__ void conv_x_kernel(const float* __restrict__ x, uint32_t* __restrict__ dst) {
    int i = blockIdx.x * 256 + threadIdx.x;   // exactly X0_DW threads
    float v0 = x[2 * i], v1 = x[2 * i + 1];
    half2v h = {(_Float16)v0, (_Float16)v1};
    dst[i] = __builtin_bit_cast(uint32_t, h);
}

// dst layout: [k(64)][wave(8)][c4(32)][lane(64)][e(4)].
// Column space (halves): [0,1024) = x region (cols >= din zero-padded),
//                        [1024,2048) = h region.
__global__ void pack_weights_kernel(const float* __restrict__ wih, const float* __restrict__ whh,
                                    int din, uint32_t* __restrict__ dst) {
    int i = blockIdx.x * 256 + threadIdx.x;   // exactly WL_DW threads
    int e = i & 3;  int q = i >> 2;
    int l = q & 63; q >>= 6;
    int c4 = q & 31; q >>= 5;
    int w = q & 7;  int k = q >> 3;
    int c = 4 * c4 + e;
    int col = w * 256 + 2 * c;                // half col in [0,2048)
    int row = (l >> 4) * HID + k * 16 + (l & 15);
    float v0, v1;
    {
        int hc = col;
        v0 = (hc < 1024) ? ((hc < din) ? wih[(size_t)row * din + hc] : 0.f)
                         : whh[(size_t)row * HID + (hc - 1024)];
        hc = col + 1;
        v1 = (hc < 1024) ? ((hc < din) ? wih[(size_t)row * din + hc] : 0.f)
                         : whh[(size_t)row * HID + (hc - 1024)];
    }
    half2v h = {(_Float16)v0, (_Float16)v1};
    dst[i] = __builtin_bit_cast(uint32_t, h);
}

__global__ void init_misc_kernel(int* __restrict__ flags, int n, float* __restrict__ out,
                                 const float* __restrict__ fcb) {
    int i = blockIdx.x * 256 + threadIdx.x;
    if (i < n) flags[i] = 0;
    if (i == 0) out[0] = fcb[0];
}

// ---------------- persistent LSTM kernel ----------------

__device__ __forceinline__ float fsigmoid(float x) { return 1.f / (1.f + __expf(-x)); }
__device__ __forceinline__ float ftanh_c(float x) {
    float e = __expf(-2.f * x);
    return (1.f - e) / (1.f + e);
}

// Poll 4 consecutive tagged dwords until all carry `tag` in low 16 bits.
__device__ __forceinline__ v4u poll4(const uint32_t* p, uint32_t tag, int* abortf) {
    v4u d;
    int tries = 0;
    for (;;) {
        uint64_t a = ALOAD((const uint64_t*)p);
        uint64_t b = ALOAD((const uint64_t*)(p + 2));
        d[0] = (uint32_t)a; d[1] = (uint32_t)(a >> 32);
        d[2] = (uint32_t)b; d[3] = (uint32_t)(b >> 32);
        uint32_t bad = ((d[0] ^ tag) | (d[1] ^ tag) | (d[2] ^ tag) | (d[3] ^ tag)) & 0xFFFFu;
        if (bad == 0) break;
        if ((++tries & 255) == 0) {
            if (ALOAD(abortf)) break;
            if (tries > (1 << 22)) { ASTORE(abortf, 1); break; }
        }
    }
    return d;
}

__device__ __forceinline__ void run_layer(
    int k, bool isL0,
    const uint32_t* __restrict__ x0p,     // layer 0 input (packed halves, untagged)
    const uint32_t* up_ring,              // upstream tagged ring (null for L0)
    uint32_t* own_ring,                   // own tagged ring
    const uint32_t* __restrict__ wsrc,
    const float* __restrict__ bias,
    const float* __restrict__ fcw,
    float* out,
    int* prog_own, int* prog_dn, int* abortf, bool doFC)
{
    __shared__ alignas(16) uint32_t in_lds[NWAVE * SP];   // 1024 dw = 4 KB
    __shared__ float red[NWAVE][65];                      // +1 pad vs bank aliasing

    const int tid  = threadIdx.x;
    const int wave = tid >> 6;
    const int lane = tid & 63;

    // ---- weight slice -> AGPRs (128/thread). AGPR class has no competing
    //      users, so these stay resident for the whole kernel (proven in R4:
    //      VALUBusy delta showed the reads executing at full occupancy).
    uint32_t aw[SP];
    {
        const uint32_t* wbp = wsrc + (size_t)wave * (SP * 64) + lane * 4;
#pragma unroll
        for (int c4 = 0; c4 < 32; ++c4) {
            v4u tv = *(const v4u*)(wbp + (size_t)c4 * 256);
            asm volatile("v_accvgpr_write_b32 %0, %1" : "=a"(aw[4 * c4 + 0]) : "v"(tv[0]));
            asm volatile("v_accvgpr_write_b32 %0, %1" : "=a"(aw[4 * c4 + 1]) : "v"(tv[1]));
            asm volatile("v_accvgpr_write_b32 %0, %1" : "=a"(aw[4 * c4 + 2]) : "v"(tv[2]));
            asm volatile("v_accvgpr_write_b32 %0, %1" : "=a"(aw[4 * c4 + 3]) : "v"(tv[3]));
        }
    }

    // per-lane gate-row mapping for the distributed epilogue:
    // rs=lane>>3, part=lane&7; row = 2*wave + (rs&1) + 16*(rs>>1)
    const int part = lane & 7;
    const int rs   = lane >> 3;
    const int row  = 2 * wave + (rs & 1) + 16 * (rs >> 1);
    const bool owner = ((lane & 0x37) == 0);              // lanes 0, 8
    const int hidx = k * 16 + 2 * wave + (lane >> 3);     // valid on owner lanes

    const float bval = bias[(row >> 4) * HID + k * 16 + (row & 15)];
    float fcv = 0.f;
    if (owner && doFC) fcv = fcw[hidx];
    float cst = 0.f, hval = 0.f;

    for (int t = 0; t < S_LEN; ++t) {
        const int slot = t & RMASK;

        // ---- rare ring-overrun guard (off critical path; every 64 steps) ----
        if (prog_dn && wave == 0 && t >= RING && (t & 63) == 0) {
            int it = 0;
            for (;;) {
                int ok = (ALOAD(prog_dn + lane) >= t - RING + 64);
                if (__all(ok)) break;
                if ((++it & 255) == 0) {
                    if (ALOAD(abortf)) break;
                    if (it > (1 << 22)) { ASTORE(abortf, 1); break; }
                }
            }
        }

        // ---- stage [x(512dw) | h_{t-1}(512dw)] into LDS via tagged polls ----
        {
            uint32_t dw0, dw1;
            if (tid < 256) {
                if (isL0) {
                    uint64_t v = 0;
                    if (tid < 64) v = *(const uint64_t*)(x0p + (size_t)t * 128 + 2 * tid);
                    dw0 = (uint32_t)v; dw1 = (uint32_t)(v >> 32);
                } else {
                    v4u d = poll4(up_ring + (size_t)slot * HID + 4 * tid, (uint32_t)t, abortf);
                    dw0 = (d[0] >> 16) | (d[1] & 0xFFFF0000u);
                    dw1 = (d[2] >> 16) | (d[3] & 0xFFFF0000u);
                }
            } else {
                if (t) {
                    v4u d = poll4(own_ring + (size_t)((t - 1) & RMASK) * HID + 4 * (tid - 256),
                                  (uint32_t)(t - 1), abortf);
                    dw0 = (d[0] >> 16) | (d[1] & 0xFFFF0000u);
                    dw1 = (d[2] >> 16) | (d[3] & 0xFFFF0000u);
                } else { dw0 = 0u; dw1 = 0u; }
            }
            in_lds[2 * tid] = dw0;
            in_lds[2 * tid + 1] = dw1;
        }
        __syncthreads();

        // ---- dot: lane = gate row, wave = 256-half column slice ----
        const uint32_t* wi = in_lds + wave * SP;
        float a0 = 0, a1 = 0, a2 = 0, a3 = 0;
#define DOT(i) { v4u x_ = *(const v4u*)&wi[4 * (i)];                              \
        uint32_t w0, w1, w2, w3;                                                  \
        asm volatile("v_accvgpr_read_b32 %0, %1" : "=v"(w0) : "a"(aw[4*(i)+0]));  \
        asm volatile("v_accvgpr_read_b32 %0, %1" : "=v"(w1) : "a"(aw[4*(i)+1]));  \
        asm volatile("v_accvgpr_read_b32 %0, %1" : "=v"(w2) : "a"(aw[4*(i)+2]));  \
        asm volatile("v_accvgpr_read_b32 %0, %1" : "=v"(w3) : "a"(aw[4*(i)+3]));  \
        a0 = dot2acc(w0, x_[0], a0);                                              \
        a1 = dot2acc(w1, x_[1], a1);                                              \
        a2 = dot2acc(w2, x_[2], a2);                                              \
        a3 = dot2acc(w3, x_[3], a3); }
        DOT(0) DOT(1) DOT(2) DOT(3)
        __builtin_amdgcn_sched_barrier(0);
        DOT(4) DOT(5) DOT(6) DOT(7)
        __builtin_amdgcn_sched_barrier(0);
        DOT(8) DOT(9) DOT(10) DOT(11)
        __builtin_amdgcn_sched_barrier(0);
        DOT(12) DOT(13) DOT(14) DOT(15)
        __builtin_amdgcn_sched_barrier(0);
        DOT(16) DOT(17) DOT(18) DOT(19)
        __builtin_amdgcn_sched_barrier(0);
        DOT(20) DOT(21) DOT(22) DOT(23)
        __builtin_amdgcn_sched_barrier(0);
        DOT(24) DOT(25) DOT(26) DOT(27)
        __builtin_amdgcn_sched_barrier(0);
        DOT(28) DOT(29) DOT(30) DOT(31)
#undef DOT
        red[wave][lane] = (a0 + a1) + (a2 + a3);
        __syncthreads();

        // ---- distributed epilogue: each wave finalizes 2 h-outputs ----
        {
            float p = red[part][row];
            p += __shfl_xor(p, 1);
            p += __shfl_xor(p, 2);
            p += __shfl_xor(p, 4);
            p += bval;
            p = fminf(15.f, fmaxf(-15.f, p));
            float pf = __shfl(p, (lane + 16) & 63);
            float pg = __shfl(p, (lane + 32) & 63);
            float po = __shfl(p, (lane + 48) & 63);
            if (owner) {
                float ig = fsigmoid(p);
                float fg = fsigmoid(pf);
                float gg = ftanh_c(pg);
                float og = fsigmoid(po);
                cst = fg * cst + ig * gg;
                float c2 = fminf(15.f, fmaxf(-15.f, cst));
                hval = og * ftanh_c(c2);
                uint32_t hb = (uint32_t)__builtin_bit_cast(unsigned short, (_Float16)hval);
                ASTORE(own_ring + (size_t)slot * HID + hidx, (hb << 16) | ((uint32_t)t & 0xFFFFu));
            }
        }

        if (((t & 63) == 63) && tid == 0) ASTORE(prog_own + k, t);
    }

    // ---- final FC (layer 3): y = fc_w . h_last + fc_b ----
    if (doFC) {
        float p = owner ? fcv * hval : 0.f;
#pragma unroll
        for (int o = 32; o; o >>= 1) p += __shfl_xor(p, o);
        if (lane == 0) atomicAdd(out, p);
    }
}

__global__ __launch_bounds__(NTHR, 2) __attribute__((amdgpu_waves_per_eu(2, 2)))
void lstm_persistent(
    const uint32_t* __restrict__ x0p,
    uint32_t* ring,
    const uint32_t* __restrict__ wp,
    const float* __restrict__ b0, const float* __restrict__ b1,
    const float* __restrict__ b2, const float* __restrict__ b3,
    const float* __restrict__ fcw, float* out,
    int* flags, int* abortf)
{
    const int bid = blockIdx.x;
    const int xcd = bid & 7;
    const int layer = xcd >> 1;                    // 2 XCDs per layer
    const int k = ((bid >> 3) << 1) | (xcd & 1);   // 0..63 within layer

    const float* bias = (layer == 0) ? b0 : (layer == 1) ? b1 : (layer == 2) ? b2 : b3;
    int* prog_own = flags + layer * NCU_L;
    int* prog_dn  = (layer < 3) ? (flags + (layer + 1) * NCU_L) : nullptr;

    uint32_t* own_ring = ring + (size_t)layer * RING * HID;
    const uint32_t* up_ring = layer ? (ring + (size_t)(layer - 1) * RING * HID) : nullptr;
    const uint32_t* wsrc = wp + (size_t)layer * WL_DW + (size_t)k * WK_DW;

    run_layer(k, layer == 0, x0p, up_ring, own_ring, wsrc, bias, fcw, out,
              prog_own, prog_dn, abortf, layer == 3);
}

// ---------------- host launcher ----------------

extern "C" void kernel_launch(void* const* d_in, const int* in_sizes, int n_in,
                              void* d_out, int out_size, void* d_ws, size_t ws_size,
                              hipStream_t stream) {
    const float* seq  = (const float*)d_in[0];
    const float* wih0 = (const float*)d_in[1];
    const float* whh0 = (const float*)d_in[2];
    const float* b0   = (const float*)d_in[3];
    const float* wih1 = (const float*)d_in[4];
    const float* whh1 = (const float*)d_in[5];
    const float* b1   = (const float*)d_in[6];
    const float* wih2 = (const float*)d_in[7];
    const float* whh2 = (const float*)d_in[8];
    const float* b2   = (const float*)d_in[9];
    const float* wih3 = (const float*)d_in[10];
    const float* whh3 = (const float*)d_in[11];
    const float* b3   = (const float*)d_in[12];
    const float* fcw  = (const float*)d_in[13];
    const float* fcb  = (const float*)d_in[14];
    float* out = (float*)d_out;

    if (ws_size < TOTAL_WS) return;

    uint8_t* ws = (uint8_t*)d_ws;
    uint32_t* x0p  = (uint32_t*)ws;
    uint32_t* ring = (uint32_t*)(ws + X0B);
    uint32_t* wp   = (uint32_t*)(ws + X0B + RINGB);
    int* flags     = (int*)(ws + X0B + RINGB + WB);
    int* abortf    = flags + NL * NCU_L;

    conv_x_kernel<<<(int)(X0_DW / 256), 256, 0, stream>>>(seq, x0p);
    pack_weights_kernel<<<(int)(WL_DW / 256), 256, 0, stream>>>(wih0, whh0, DIN0, wp);
    pack_weights_kernel<<<(int)(WL_DW / 256), 256, 0, stream>>>(wih1, whh1, HID, wp + WL_DW);
    pack_weights_kernel<<<(int)(WL_DW / 256), 256, 0, stream>>>(wih2, whh2, HID, wp + 2 * WL_DW);
    pack_weights_kernel<<<(int)(WL_DW / 256), 256, 0, stream>>>(wih3, whh3, HID, wp + 3 * WL_DW);
    init_misc_kernel<<<(int)((FLAG_N + 255) / 256), 256, 0, stream>>>(flags, (int)FLAG_N, out, fcb);

    lstm_persistent<<<256, NTHR, 0, stream>>>(x0p, ring, wp, b0, b1, b2, b3, fcw, out, flags, abortf);
}